// Round 1
// baseline (500.083 us; speedup 1.0000x reference)
//
#include <hip/hip_runtime.h>
#include <hip/hip_bf16.h>

// ---------------------------------------------------------------------------
// MLPpara: out = softmax( selu( selu( (mag ⊙ (x@W_pre[e]) + b_pre[e]) @ W_share
//                  + b_share ) @ W1 + b1 ) @ W2 + b2 )
// Fused single main kernel: 1 block per expert (256 blocks = 256 CUs),
// 512 threads = 8 waves (4 M-rows x 2 N-cols).
// HBM-bound on W_pre (268 MB f32 streamed once). bf16 MFMA 16x16x32.
// ---------------------------------------------------------------------------

typedef float  f32x4  __attribute__((ext_vector_type(4)));
typedef __bf16 bf16x8 __attribute__((ext_vector_type(8)));
typedef int    i32x4  __attribute__((ext_vector_type(4)));

#define MFMA16(a, b, c) __builtin_amdgcn_mfma_f32_16x16x32_bf16((a), (b), (c), 0, 0, 0)

static constexpr int NE = 256, NB = 256, NP = 512, NS = 200, NT = 20;

// LDS pitches (in bf16 elements); all row strides are 16B-aligned for ds_read_b128
static constexpr int XS_P = 40;   // x slice  [256][32] (+8 pad)  -> 80B pitch
static constexpr int ST_P = 40;   // W slice  [64 q][32 p] (+8)   -> 80B pitch (transposed!)
static constexpr int HT_P = 72;   // h tile   [256][64] (+8)      -> 144B pitch
static constexpr int H2_P = 232;  // h2       [256][224] (+8)     -> 464B pitch

// LDS byte offsets (phase-2 overlays phase-1)
static constexpr int OFF_XS   = 0;                      // 2*256*40*2 = 40960
static constexpr int OFF_ST   = 40960;                  // 2*64*40*2  = 10240
static constexpr int OFF_HT   = 51200;                  // 256*72*2   = 36864 (end 88064)
static constexpr int OFF_H2   = 0;                      // 256*232*2  = 118784
static constexpr int OFF_PART = 118784;                 // 512*2*4    = 4096
static constexpr int SMEM_BYTES = 122880;               // <= 160 KiB

// ---------------------------- prep kernels ---------------------------------

__global__ void prep_x(const float* __restrict__ x, __bf16* __restrict__ xb) {
    int i = blockIdx.x * 256 + threadIdx.x;          // 131072 total
    xb[i] = (__bf16)x[i];
}

// W_share [512][200] f32 -> MFMA B-fragment order, padded to 224 cols, bf16.
// layout: [(k32 0..15)][(n16 0..13)][lane 0..63][elem 0..7]
__global__ void prep_ws(const float* __restrict__ Ws, __bf16* __restrict__ wf) {
    int i = blockIdx.x * 256 + threadIdx.x;          // 114688 total
    int e8  = i & 7;
    int l   = (i >> 3) & 63;
    int n16 = (i >> 9) % 14;
    int k32 = (i >> 9) / 14;
    int q = k32 * 32 + (l >> 4) * 8 + e8;            // contraction index (0..511)
    int s = n16 * 16 + (l & 15);                     // output col (0..223)
    float v = (s < NS) ? Ws[q * NS + s] : 0.0f;
    wf[i] = (__bf16)v;
}

// ---------------------------- main kernel ----------------------------------

__global__ __launch_bounds__(512, 2) void fused_experts(
    const float* __restrict__ mag,     // [E][B]
    const float* __restrict__ Wpre,    // [E][P][P]
    const float* __restrict__ bpre,    // [E][P]
    const float* __restrict__ bshare,  // [S]
    const float* __restrict__ W1,      // [S][T]
    const float* __restrict__ b1,      // [T]
    const float* __restrict__ W2,      // [T][2]
    const float* __restrict__ b2,      // [2]
    const __bf16* __restrict__ xb,     // [B][P] bf16
    const __bf16* __restrict__ wsf,    // W_share fragments
    float* __restrict__ out)           // [E*B][2]
{
    __shared__ __align__(16) char smem[SMEM_BYTES];
    __bf16* xs = (__bf16*)(smem + OFF_XS);
    __bf16* st = (__bf16*)(smem + OFF_ST);
    __bf16* ht = (__bf16*)(smem + OFF_HT);

    const int e    = blockIdx.x;
    const int tid  = threadIdx.x;
    const int lane = tid & 63;
    const int wid  = tid >> 6;
    const int wr   = wid >> 1;     // 0..3 : 64-row band
    const int wc   = wid & 1;      // 0..1 : N column half
    const int l15  = lane & 15;
    const int lg   = lane >> 4;    // 0..3

    // staging roles (all 512 threads)
    const int sx_b = tid >> 1;            // x stage: row 0..255
    const int sx_h = tid & 1;             // which 16-k half
    const int sw_p = tid >> 4;            // W stage: p row 0..31
    const int sw_q = (tid & 15) * 4;      // W stage: q group

    const float* WpreE = Wpre + (size_t)e * NP * NP;

    // GEMM2 persistent accumulators: rows [wr*64,+64), cols [wc*112,+112)
    f32x4 acc2[4][7];
#pragma unroll
    for (int i = 0; i < 4; i++)
#pragma unroll
        for (int j = 0; j < 7; j++)
            acc2[i][j] = (f32x4){0.f, 0.f, 0.f, 0.f};

    for (int nt = 0; nt < 8; ++nt) {
        // ---- GEMM1: Y[:, nt*64..+64) = x @ W_pre[e][:, nt-cols] ----
        f32x4 acc1[4][2];
#pragma unroll
        for (int i = 0; i < 4; i++)
#pragma unroll
            for (int j = 0; j < 2; j++)
                acc1[i][j] = (f32x4){0.f, 0.f, 0.f, 0.f};

        // prologue: stage k=0 into buffer 0
        {
            i32x4 rx0 = *(const i32x4*)(xb + sx_b * NP + sx_h * 16);
            i32x4 rx1 = *(const i32x4*)(xb + sx_b * NP + sx_h * 16 + 8);
            f32x4 rw  = *(const f32x4*)(WpreE + (size_t)sw_p * NP + nt * 64 + sw_q);
            *(i32x4*)(xs + sx_b * XS_P + sx_h * 16)     = rx0;
            *(i32x4*)(xs + sx_b * XS_P + sx_h * 16 + 8) = rx1;
#pragma unroll
            for (int ii = 0; ii < 4; ++ii)   // transposed store: st[q][p]
                st[(sw_q + ii) * ST_P + sw_p] = (__bf16)rw[ii];
        }
        __syncthreads();

#pragma unroll 2
        for (int k = 0; k < 16; ++k) {
            const int db = k & 1;
            // issue next-slice global loads early (depth-1 prefetch)
            i32x4 nx0, nx1; f32x4 nw;
            if (k < 15) {
                const int k32 = k + 1;
                nx0 = *(const i32x4*)(xb + sx_b * NP + k32 * 32 + sx_h * 16);
                nx1 = *(const i32x4*)(xb + sx_b * NP + k32 * 32 + sx_h * 16 + 8);
                nw  = *(const f32x4*)(WpreE + (size_t)(k32 * 32 + sw_p) * NP + nt * 64 + sw_q);
            }
            // A fragments from xs: row = l15, k-contiguous 8 elems per lane
            bf16x8 af[4], bfr[2];
            const __bf16* xsb = xs + db * (256 * XS_P);
#pragma unroll
            for (int i = 0; i < 4; i++) {
                const int row = wr * 64 + i * 16 + l15;
                af[i] = *(const bf16x8*)(xsb + row * XS_P + lg * 8);
            }
            // B fragments from st (transposed [q][p] so k (=p) is contiguous)
            const __bf16* stb = st + db * (64 * ST_P);
#pragma unroll
            for (int j = 0; j < 2; j++) {
                const int q = wc * 32 + j * 16 + l15;
                bfr[j] = *(const bf16x8*)(stb + q * ST_P + lg * 8);
            }
#pragma unroll
            for (int i = 0; i < 4; i++)
#pragma unroll
                for (int j = 0; j < 2; j++)
                    acc1[i][j] = MFMA16(af[i], bfr[j], acc1[i][j]);

            if (k < 15) {
                const int nb2 = 1 - db;
                *(i32x4*)(xs + nb2 * (256 * XS_P) + sx_b * XS_P + sx_h * 16)     = nx0;
                *(i32x4*)(xs + nb2 * (256 * XS_P) + sx_b * XS_P + sx_h * 16 + 8) = nx1;
                __bf16* stw = st + nb2 * (64 * ST_P);
#pragma unroll
                for (int ii = 0; ii < 4; ++ii)
                    stw[(sw_q + ii) * ST_P + sw_p] = (__bf16)nw[ii];
            }
            __syncthreads();
        }

        // ---- h = mag*Y + b_pre -> bf16 h-tile in LDS ----
        // D layout: col = lane&15 (q), row = (lane>>4)*4 + r (b)   [m89-verified]
#pragma unroll
        for (int j = 0; j < 2; j++) {
            const int qg = nt * 64 + wc * 32 + j * 16 + l15;
            const float bp = bpre[e * NP + qg];
#pragma unroll
            for (int i = 0; i < 4; i++) {
                const int b0 = wr * 64 + i * 16 + lg * 4;
#pragma unroll
                for (int r = 0; r < 4; r++) {
                    const float m = mag[e * NB + b0 + r];
                    const float h = m * acc1[i][j][r] + bp;
                    ht[(b0 + r) * HT_P + wc * 32 + j * 16 + l15] = (__bf16)h;
                }
            }
        }
        __syncthreads();

        // ---- GEMM2 partial: Z += h_tile[256x64] @ W_share[64 x 224] ----
#pragma unroll
        for (int kk = 0; kk < 2; ++kk) {
            const int k32g = nt * 2 + kk;   // global q/32
            bf16x8 b2f[7], a2[4];
#pragma unroll
            for (int j2 = 0; j2 < 7; j2++) {
                const int n16 = wc * 7 + j2;
                b2f[j2] = *(const bf16x8*)(wsf + (size_t)((k32g * 14 + n16) * 64 + lane) * 8);
            }
#pragma unroll
            for (int i = 0; i < 4; i++) {
                const int row = wr * 64 + i * 16 + l15;
                a2[i] = *(const bf16x8*)(ht + row * HT_P + kk * 32 + lg * 8);
            }
#pragma unroll
            for (int i = 0; i < 4; i++)
#pragma unroll
                for (int j2 = 0; j2 < 7; j2++)
                    acc2[i][j2] = MFMA16(a2[i], b2f[j2], acc2[i][j2]);
        }
        __syncthreads();
    } // nt

    // ------------------------------ tail -----------------------------------
    __bf16* h2  = (__bf16*)(smem + OFF_H2);
    float* part = (float*)(smem + OFF_PART);
    const float SC = 1.0507009873554805f;   // selu scale
    const float AL = 1.6732632423543772f;   // selu alpha

    // h2 = selu(Z + b_share) as bf16 (overlays dead phase-1 buffers)
#pragma unroll
    for (int j2 = 0; j2 < 7; j2++) {
        const int s = wc * 112 + j2 * 16 + l15;
        const float bs = (s < NS) ? bshare[s] : 0.0f;
#pragma unroll
        for (int i = 0; i < 4; i++) {
            const int b0 = wr * 64 + i * 16 + lg * 4;
#pragma unroll
            for (int r = 0; r < 4; r++) {
                float z = acc2[i][j2][r] + bs;
                z = (z > 0.f) ? SC * z : SC * AL * (__expf(z) - 1.f);
                h2[(b0 + r) * H2_P + s] = (__bf16)z;
            }
        }
    }
    __syncthreads();

    // GEMM3 (200->20) + SELU + partial GEMM4, f32 VALU.
    // thread = b + 256*th, th picks 10 of the 20 hidden units (wave-uniform).
    {
        const int b  = tid & 255;
        const int th = tid >> 8;
        float u[10];
#pragma unroll
        for (int j = 0; j < 10; j++) u[j] = b1[th * 10 + j];
        for (int s8 = 0; s8 < NS; s8 += 8) {
            bf16x8 hv = *(const bf16x8*)(h2 + b * H2_P + s8);
#pragma unroll
            for (int so = 0; so < 8; so++) {
                const float v = (float)hv[so];
                const float* w1row = W1 + (s8 + so) * NT + th * 10;  // wave-uniform -> s_loads
#pragma unroll
                for (int j = 0; j < 10; j++) u[j] = fmaf(v, w1row[j], u[j]);
            }
        }
        float p0 = 0.f, p1 = 0.f;
#pragma unroll
        for (int j = 0; j < 10; j++) {
            float v = u[j];
            v = (v > 0.f) ? SC * v : SC * AL * (__expf(v) - 1.f);
            const int t = th * 10 + j;
            p0 = fmaf(v, W2[t * 2 + 0], p0);
            p1 = fmaf(v, W2[t * 2 + 1], p1);
        }
        part[tid * 2 + 0] = p0;
        part[tid * 2 + 1] = p1;
    }
    __syncthreads();

    if (tid < 256) {
        const int b = tid;
        const float l0 = part[b * 2 + 0] + part[(b + 256) * 2 + 0] + b2[0];
        const float l1 = part[b * 2 + 1] + part[(b + 256) * 2 + 1] + b2[1];
        const float mx  = fmaxf(l0, l1);
        const float ex0 = __expf(l0 - mx), ex1 = __expf(l1 - mx);
        const float inv = 1.0f / (ex0 + ex1);
        out[((size_t)e * NB + b) * 2 + 0] = ex0 * inv;
        out[((size_t)e * NB + b) * 2 + 1] = ex1 * inv;
    }
}

// ---------------------------- launcher -------------------------------------

extern "C" void kernel_launch(void* const* d_in, const int* in_sizes, int n_in,
                              void* d_out, int out_size, void* d_ws, size_t ws_size,
                              hipStream_t stream) {
    const float* x      = (const float*)d_in[0];
    const float* mag    = (const float*)d_in[1];
    const float* Wpre   = (const float*)d_in[2];
    const float* bpre   = (const float*)d_in[3];
    const float* Wshare = (const float*)d_in[4];
    const float* bshare = (const float*)d_in[5];
    const float* W1     = (const float*)d_in[6];
    const float* b1     = (const float*)d_in[7];
    const float* W2     = (const float*)d_in[8];
    const float* b2     = (const float*)d_in[9];
    float* out = (float*)d_out;

    __bf16* xb  = (__bf16*)d_ws;                        // 262144 B
    __bf16* wsf = (__bf16*)((char*)d_ws + 262144);      // 229376 B

    prep_x <<<512, 256, 0, stream>>>(x, xb);
    prep_ws<<<448, 256, 0, stream>>>(Wshare, wsf);
    fused_experts<<<256, 512, 0, stream>>>(mag, Wpre, bpre, bshare, W1, b1,
                                           W2, b2, xb, wsf, out);
}

// Round 2
// 483.432 us; speedup vs baseline: 1.0344x; 1.0344x over previous
//
#include <hip/hip_runtime.h>
#include <hip/hip_bf16.h>

// ---------------------------------------------------------------------------
// MLPpara fused:  out = softmax( selu( selu( (mag ⊙ (x@W_pre[e]) + b_pre[e])
//                        @ W_share + b_share ) @ W1 + b1 ) @ W2 + b2 )
// 1 block / expert (256 blocks = 256 CUs), 512 threads = 8 waves (4 M x 2 N).
// HBM-bound on W_pre stream. Pipeline: raw s_barrier + lgkm-only drains so
// global prefetches stay in flight across barriers; depth-2 W prefetch.
// x pre-arranged in MFMA fragment order (read from L2, no LDS staging).
// ---------------------------------------------------------------------------

typedef float  f32x4  __attribute__((ext_vector_type(4)));
typedef __bf16 bf16x8 __attribute__((ext_vector_type(8)));
typedef __bf16 bf16x4 __attribute__((ext_vector_type(4)));
typedef int    i32x2  __attribute__((ext_vector_type(2)));
typedef int    i32x4  __attribute__((ext_vector_type(4)));

#define MFMA16(a, b, c) __builtin_amdgcn_mfma_f32_16x16x32_bf16((a), (b), (c), 0, 0, 0)

static constexpr int NB = 256, NP = 512, NS = 200;

// LDS map (bytes)
static constexpr int ST_PITCH = 72;              // q-row pitch: 64B payload + 8B pad
static constexpr int ST_BUF   = 64 * ST_PITCH;   // 4608 per buffer
static constexpr int OFF_ST   = 0;               // 2 buffers: 9216
static constexpr int OFF_HT   = 9216;            // h tile 256 rows x 144B = 36864
static constexpr int HT_PITCH = 144;             // 64 bf16 payload + 16B pad (16B aligned)
static constexpr int H2_P     = 232;             // tail h2 pitch (elements)
static constexpr int OFF_H2   = 0;               // overlay after full sync
static constexpr int OFF_PART = 118784;          // 512*2*4 = 4096
static constexpr int SMEM_BYTES = 122880;

#define LGKM_BARRIER()                                        \
    do {                                                      \
        asm volatile("s_waitcnt lgkmcnt(0)" ::: "memory");    \
        __builtin_amdgcn_s_barrier();                         \
    } while (0)

// ---------------------------- prep kernels ---------------------------------

// x [256][512] f32 -> A-fragment order bf16: idx = ((k32*16 + r16)*64 + lane)*8 + e
// maps to x[r16*16 + (lane&15)][k32*32 + (lane>>4)*8 + e]
__global__ void prep_xf(const float* __restrict__ x, __bf16* __restrict__ xf) {
    int t   = blockIdx.x * 256 + threadIdx.x;    // 16384 total
    int l   = t & 63;
    int r16 = (t >> 6) & 15;
    int k32 = t >> 10;
    const float* src = x + (r16 * 16 + (l & 15)) * NP + k32 * 32 + (l >> 4) * 8;
    bf16x8 v;
#pragma unroll
    for (int e = 0; e < 8; e++) v[e] = (__bf16)src[e];
    *(bf16x8*)(xf + (size_t)t * 8) = v;
}

// W_share [512][200] f32 -> MFMA B-fragment order, padded to 224 cols, bf16.
// layout: [(k32 0..15)][(n16 0..13)][lane 0..63][elem 0..7]
__global__ void prep_ws(const float* __restrict__ Ws, __bf16* __restrict__ wf) {
    int i = blockIdx.x * 256 + threadIdx.x;      // 114688 total
    int e8  = i & 7;
    int l   = (i >> 3) & 63;
    int n16 = (i >> 9) % 14;
    int k32 = (i >> 9) / 14;
    int q = k32 * 32 + (l >> 4) * 8 + e8;
    int s = n16 * 16 + (l & 15);
    float v = (s < NS) ? Ws[q * NS + s] : 0.0f;
    wf[i] = (__bf16)v;
}

// ---------------------------- main kernel ----------------------------------

// one k-step of GEMM1; S in [0,128): nt = S>>4, k32 = S&15
// XC: A-frags for step S (arrived). XN: loads A-frags for S+1.
// WLD: issues W slice S+2. WUSE: holds W slice S+1 (written to LDS at end).
#define K_STEP(S, XC, XN, WLD, WUSE)                                          \
    {                                                                         \
        const int s1_ = (S) + 1, s2_ = (S) + 2;                               \
        if (s1_ < 128) {                                                      \
            const int k1_ = s1_ & 15;                                         \
            _Pragma("unroll")                                                 \
            for (int i_ = 0; i_ < 4; i_++)                                    \
                XN[i_] = *(const bf16x8*)(xfw + k1_ * 8192 + i_ * 512);       \
        }                                                                     \
        if (s2_ < 128) {                                                      \
            const int nt2_ = s2_ >> 4, k2_ = s2_ & 15;                        \
            _Pragma("unroll")                                                 \
            for (int i_ = 0; i_ < 4; i_++)                                    \
                WLD[i_] = WpreE[(size_t)(k2_ * 32 + p0 + i_) * NP + nt2_ * 64 + q]; \
        }                                                                     \
        {                                                                     \
            const char* stb_ = smem + OFF_ST + ((S) & 1) * ST_BUF;            \
            bf16x8 bf_[2];                                                    \
            _Pragma("unroll")                                                 \
            for (int j_ = 0; j_ < 2; j_++) {                                  \
                const int q_ = wc * 32 + j_ * 16 + l15;                       \
                union { i32x4 u; bf16x8 b; } cv_;                             \
                i32x2 lo_ = *(const i32x2*)(stb_ + q_ * ST_PITCH + lg * 16);  \
                i32x2 hi_ = *(const i32x2*)(stb_ + q_ * ST_PITCH + lg * 16 + 8); \
                cv_.u = (i32x4){lo_.x, lo_.y, hi_.x, hi_.y};                  \
                bf_[j_] = cv_.b;                                              \
            }                                                                 \
            _Pragma("unroll")                                                 \
            for (int i_ = 0; i_ < 4; i_++)                                    \
                _Pragma("unroll")                                             \
                for (int j_ = 0; j_ < 2; j_++)                                \
                    acc1[i_][j_] = MFMA16(XC[i_], bf_[j_], acc1[i_][j_]);     \
        }                                                                     \
        if (s1_ < 128) {                                                      \
            bf16x4 wv_;                                                       \
            _Pragma("unroll")                                                 \
            for (int i_ = 0; i_ < 4; i_++) wv_[i_] = (__bf16)WUSE[i_];        \
            *(bf16x4*)(smem + OFF_ST + (s1_ & 1) * ST_BUF + q * ST_PITCH + p0 * 2) = wv_; \
        }                                                                     \
        LGKM_BARRIER();                                                       \
    }

__global__ __launch_bounds__(512, 2) void fused_experts(
    const float* __restrict__ mag,     // [E][B]
    const float* __restrict__ Wpre,    // [E][P][P]
    const float* __restrict__ bpre,    // [E][P]
    const float* __restrict__ bshare,  // [S]
    const float* __restrict__ W1,      // [S][T]
    const float* __restrict__ b1,      // [T]
    const float* __restrict__ W2,      // [T][2]
    const float* __restrict__ b2,      // [2]
    const __bf16* __restrict__ xf,     // x in A-frag order
    const __bf16* __restrict__ wsf,    // W_share B-frags
    float* __restrict__ out)           // [E*B][2]
{
    __shared__ __align__(16) char smem[SMEM_BYTES];

    const int e    = blockIdx.x;
    const int tid  = threadIdx.x;
    const int lane = tid & 63;
    const int wid  = tid >> 6;
    const int wr   = wid >> 1;       // 0..3 : 64-row band
    const int wc   = wid & 1;        // 0..1 : N half
    const int l15  = lane & 15;
    const int lg   = lane >> 4;

    // W staging role: thread gathers W[p0..p0+3][q] (4 coalesced dword loads)
    const int q  = tid & 63;
    const int p0 = (tid >> 6) * 4;

    const float* WpreE = Wpre + (size_t)e * NP * NP;
    const __bf16* xfw  = xf + (wr * 4 * 64 + lane) * 8;

    // mag preload: 16 values per lane covering rows wr*64 + i*16 + lg*4 + r
    f32x4 magv[4];
#pragma unroll
    for (int i = 0; i < 4; i++)
        magv[i] = *(const f32x4*)(mag + e * NB + wr * 64 + i * 16 + lg * 4);

    f32x4 acc2[4][7];
#pragma unroll
    for (int i = 0; i < 4; i++)
#pragma unroll
        for (int j = 0; j < 7; j++) acc2[i][j] = (f32x4){0.f, 0.f, 0.f, 0.f};
    f32x4 acc1[4][2];
#pragma unroll
    for (int i = 0; i < 4; i++)
#pragma unroll
        for (int j = 0; j < 2; j++) acc1[i][j] = (f32x4){0.f, 0.f, 0.f, 0.f};

    bf16x8 XA[4], XB[4];
    float  WEV[4], WOD[4], WT[4];

    // ---- prologue: x(0), W slice0 -> st[0], W slice1 in flight ----
#pragma unroll
    for (int i = 0; i < 4; i++)
        XA[i] = *(const bf16x8*)(xfw + i * 512);
#pragma unroll
    for (int i = 0; i < 4; i++)
        WT[i]  = WpreE[(size_t)(p0 + i) * NP + q];                 // slice 0
#pragma unroll
    for (int i = 0; i < 4; i++)
        WOD[i] = WpreE[(size_t)(32 + p0 + i) * NP + q];            // slice 1
    {
        bf16x4 wv;
#pragma unroll
        for (int i = 0; i < 4; i++) wv[i] = (__bf16)WT[i];
        *(bf16x4*)(smem + OFF_ST + q * ST_PITCH + p0 * 2) = wv;
    }
    LGKM_BARRIER();

    __bf16* ht = (__bf16*)(smem + OFF_HT);

    for (int ss = 0; ss < 128; ss += 2) {
        K_STEP(ss,     XA, XB, WEV, WOD);
        K_STEP(ss + 1, XB, XA, WOD, WEV);

        if ((ss & 15) == 14) {
            const int nt = ss >> 4;

            // h = mag*Y + b_pre -> bf16 h-tile (D layout: col=l15, row=lg*4+r)
            const float bp0 = bpre[e * NP + nt * 64 + wc * 32 + l15];
            const float bp1 = bpre[e * NP + nt * 64 + wc * 32 + 16 + l15];
#pragma unroll
            for (int j = 0; j < 2; j++) {
                const float bp = j ? bp1 : bp0;
#pragma unroll
                for (int i = 0; i < 4; i++) {
#pragma unroll
                    for (int r = 0; r < 4; r++) {
                        const float h = magv[i][r] * acc1[i][j][r] + bp;
                        ht[(wr * 64 + i * 16 + lg * 4 + r) * 72 + wc * 32 + j * 16 + l15] = (__bf16)h;
                    }
                }
            }
            LGKM_BARRIER();

            // GEMM2 partial: Z += h_tile[256x64] @ W_share_frag[64x224]
#pragma unroll
            for (int kk = 0; kk < 2; kk++) {
                bf16x8 wfr[7];
#pragma unroll
                for (int j2 = 0; j2 < 7; j2++)
                    wfr[j2] = *(const bf16x8*)(wsf +
                        (size_t)((((nt * 2 + kk) * 14) + wc * 7 + j2) * 64 + lane) * 8);
                bf16x8 a2[4];
#pragma unroll
                for (int i = 0; i < 4; i++)
                    a2[i] = *(const bf16x8*)(ht + (wr * 64 + i * 16 + l15) * 72 + kk * 32 + lg * 8);
#pragma unroll
                for (int i = 0; i < 4; i++)
#pragma unroll
                    for (int j2 = 0; j2 < 7; j2++)
                        acc2[i][j2] = MFMA16(a2[i], wfr[j2], acc2[i][j2]);
            }

            // reset GEMM1 accumulators for next nt
#pragma unroll
            for (int i = 0; i < 4; i++)
#pragma unroll
                for (int j = 0; j < 2; j++) acc1[i][j] = (f32x4){0.f, 0.f, 0.f, 0.f};
        }
    }

    __syncthreads();   // full drain once; tail overlays LDS

    // ------------------------------ tail -----------------------------------
    __bf16* h2  = (__bf16*)(smem + OFF_H2);
    float* part = (float*)(smem + OFF_PART);
    const float SC = 1.0507009873554805f;
    const float AL = 1.6732632423543772f;

    // h2 = selu(Z + b_share) bf16
#pragma unroll
    for (int j2 = 0; j2 < 7; j2++) {
        const int s = wc * 112 + j2 * 16 + l15;
        const float bs = (s < NS) ? bshare[s] : 0.0f;
#pragma unroll
        for (int i = 0; i < 4; i++) {
            const int b0 = wr * 64 + i * 16 + lg * 4;
#pragma unroll
            for (int r = 0; r < 4; r++) {
                float z = acc2[i][j2][r] + bs;
                z = (z > 0.f) ? SC * z : SC * AL * (__expf(z) - 1.f);
                h2[(b0 + r) * H2_P + s] = (__bf16)z;
            }
        }
    }
    __syncthreads();

    // GEMM3 (200->20) + SELU + partial GEMM4 (f32 VALU)
    {
        const int b  = tid & 255;
        const int th = tid >> 8;
        float u[10];
#pragma unroll
        for (int j = 0; j < 10; j++) u[j] = b1[th * 10 + j];
        for (int s8 = 0; s8 < NS; s8 += 8) {
            bf16x8 hv = *(const bf16x8*)(h2 + b * H2_P + s8);
#pragma unroll
            for (int so = 0; so < 8; so++) {
                const float v = (float)hv[so];
                const float* w1row = W1 + (s8 + so) * 20 + th * 10;
#pragma unroll
                for (int j = 0; j < 10; j++) u[j] = fmaf(v, w1row[j], u[j]);
            }
        }
        float pa = 0.f, pb = 0.f;
#pragma unroll
        for (int j = 0; j < 10; j++) {
            float v = u[j];
            v = (v > 0.f) ? SC * v : SC * AL * (__expf(v) - 1.f);
            const int t = th * 10 + j;
            pa = fmaf(v, W2[t * 2 + 0], pa);
            pb = fmaf(v, W2[t * 2 + 1], pb);
        }
        part[tid * 2 + 0] = pa;
        part[tid * 2 + 1] = pb;
    }
    __syncthreads();

    if (tid < 256) {
        const int b = tid;
        const float l0 = part[b * 2 + 0] + part[(b + 256) * 2 + 0] + b2[0];
        const float l1 = part[b * 2 + 1] + part[(b + 256) * 2 + 1] + b2[1];
        const float mx  = fmaxf(l0, l1);
        const float ex0 = __expf(l0 - mx), ex1 = __expf(l1 - mx);
        const float inv = 1.0f / (ex0 + ex1);
        out[((size_t)e * NB + b) * 2 + 0] = ex0 * inv;
        out[((size_t)e * NB + b) * 2 + 1] = ex1 * inv;
    }
}

// ---------------------------- launcher -------------------------------------

extern "C" void kernel_launch(void* const* d_in, const int* in_sizes, int n_in,
                              void* d_out, int out_size, void* d_ws, size_t ws_size,
                              hipStream_t stream) {
    const float* x      = (const float*)d_in[0];
    const float* mag    = (const float*)d_in[1];
    const float* Wpre   = (const float*)d_in[2];
    const float* bpre   = (const float*)d_in[3];
    const float* Wshare = (const float*)d_in[4];
    const float* bshare = (const float*)d_in[5];
    const float* W1     = (const float*)d_in[6];
    const float* b1     = (const float*)d_in[7];
    const float* W2     = (const float*)d_in[8];
    const float* b2     = (const float*)d_in[9];
    float* out = (float*)d_out;

    __bf16* xf  = (__bf16*)d_ws;                     // 262144 B
    __bf16* wsf = (__bf16*)((char*)d_ws + 262144);   // 229376 B

    prep_xf<<<64, 256, 0, stream>>>(x, xf);
    prep_ws<<<448, 256, 0, stream>>>(Wshare, wsf);
    fused_experts<<<256, 512, 0, stream>>>(mag, Wpre, bpre, bshare, W1, b1,
                                           W2, b2, xf, wsf, out);
}